// Round 1
// baseline (2844.684 us; speedup 1.0000x reference)
//
#include <hip/hip_runtime.h>
#include <math.h>

// Problem constants (fixed by reference):
// B=2, L=2048, D=2048, H=16, G=4, HD=128, EPS=1e-6, scale = 1/HD^2 = 1/16384
#define SEQ 2048
#define DMODEL 2048
#define NHQ 16
#define NHK 4

// ---------------------------------------------------------------------------
// Tiled fp32 GEMM: C[M,N] = A[M,K] @ B[K,N], all row-major.
// 128x128 block tile, BK=16, 256 threads, 8x8 micro-tile per thread.
// M,N multiples of 128; K multiple of 16 (true for all our shapes).
// ---------------------------------------------------------------------------
__global__ __launch_bounds__(256) void gemm_f32(const float* __restrict__ A,
                                                const float* __restrict__ B,
                                                float* __restrict__ C,
                                                int M, int N, int K) {
  __shared__ float As[16][128];   // transposed store: As[k][m]
  __shared__ float Bs[16][132];   // +4 pad so staging stores spread banks
  const int tid = threadIdx.x;
  const int bm = blockIdx.y * 128;
  const int bn = blockIdx.x * 128;
  const int tx = tid & 15;
  const int ty = tid >> 4;

  float acc[8][8];
#pragma unroll
  for (int i = 0; i < 8; i++)
#pragma unroll
    for (int j = 0; j < 8; j++) acc[i][j] = 0.0f;

  for (int k0 = 0; k0 < K; k0 += 16) {
    // Stage A tile (128 rows x 16 k): 2 threads/row, 8 floats each.
    {
      const int r = tid >> 1;
      const int c = (tid & 1) * 8;
      const float* src = A + (size_t)(bm + r) * K + (k0 + c);
      const float4 v0 = *(const float4*)(src);
      const float4 v1 = *(const float4*)(src + 4);
      As[c + 0][r] = v0.x; As[c + 1][r] = v0.y; As[c + 2][r] = v0.z; As[c + 3][r] = v0.w;
      As[c + 4][r] = v1.x; As[c + 5][r] = v1.y; As[c + 6][r] = v1.z; As[c + 7][r] = v1.w;
    }
    // Stage B tile (16 k x 128 cols): 16 threads/row, 8 floats each.
    {
      const int r = tid >> 4;
      const int c = (tid & 15) * 8;
      const float* src = B + (size_t)(k0 + r) * N + (bn + c);
      *(float4*)&Bs[r][c]     = *(const float4*)(src);
      *(float4*)&Bs[r][c + 4] = *(const float4*)(src + 4);
    }
    __syncthreads();
#pragma unroll
    for (int kk = 0; kk < 16; ++kk) {
      float a[8], b[8];
      *(float4*)&a[0] = *(const float4*)&As[kk][ty * 8];
      *(float4*)&a[4] = *(const float4*)&As[kk][ty * 8 + 4];
      *(float4*)&b[0] = *(const float4*)&Bs[kk][tx * 8];
      *(float4*)&b[4] = *(const float4*)&Bs[kk][tx * 8 + 4];
#pragma unroll
      for (int i = 0; i < 8; i++)
#pragma unroll
        for (int j = 0; j < 8; j++) acc[i][j] += a[i] * b[j];
    }
    __syncthreads();
  }
#pragma unroll
  for (int i = 0; i < 8; i++) {
    float* dst = C + (size_t)(bm + ty * 8 + i) * N + (bn + tx * 8);
    *(float4*)(dst)     = *(const float4*)&acc[i][0];
    *(float4*)(dst + 4) = *(const float4*)&acc[i][4];
  }
}

// ---------------------------------------------------------------------------
// Fused RMSNorm (over HD=128 per head) + RoPE, in place.
// buf layout: (B*L, NH*128), head-major chunks. block = (64,4): one wave per
// (token, head). Thread t holds elements d=t and d=t+64 (the RoPE pair).
// ---------------------------------------------------------------------------
__global__ __launch_bounds__(256) void rmsnorm_rope(float* __restrict__ buf, int NH,
                                                    const float* __restrict__ scale,
                                                    const float* __restrict__ cosb,
                                                    const float* __restrict__ sinb) {
  const int t = threadIdx.x;                       // 0..63
  const int head = blockIdx.y * 4 + threadIdx.y;   // grid.y = NH/4
  const int row = blockIdx.x;                      // 0..B*L-1
  const int l = row & (SEQ - 1);
  float* base = buf + ((size_t)row * NH + head) * 128;
  float v0 = base[t];
  float v1 = base[t + 64];
  float ss = v0 * v0 + v1 * v1;
#pragma unroll
  for (int m = 1; m < 64; m <<= 1) ss += __shfl_xor(ss, m);
  const float r = rsqrtf(ss * (1.0f / 128.0f) + 1e-6f);
  const float a0 = v0 * r * scale[t];
  const float a1 = v1 * r * scale[t + 64];
  const float c0 = cosb[(size_t)l * 128 + t];
  const float s0 = sinb[(size_t)l * 128 + t];
  const float c1 = cosb[(size_t)l * 128 + t + 64];
  const float s1 = sinb[(size_t)l * 128 + t + 64];
  base[t]      = a0 * c0 - a1 * s0;   // first half: x1*cos - x2*sin
  base[t + 64] = a1 * c1 + a0 * s1;   // second half: x2*cos + x1*sin
}

// ---------------------------------------------------------------------------
// Causal GQA attention, online softmax. One block per (b*H+h, q-tile of 32).
// 256 threads: row r = tid>>3 (32 rows), lane-in-row e = tid&7.
// Each thread: 4 keys in QK (kj = jj*8+e, bank-uniform), 16 out dims in PV
// (chunks c = e+8i). LDS rows padded to 132 floats for bank spread.
// ---------------------------------------------------------------------------
__global__ __launch_bounds__(256) void attention(const float* __restrict__ q,
                                                 const float* __restrict__ k,
                                                 const float* __restrict__ v,
                                                 float* __restrict__ o) {
  __shared__ float qs[32][132];
  __shared__ float ks[32][132];
  __shared__ float vs[32][132];
  __shared__ float ps[32][33];

  const int tid = threadIdx.x;
  const int bh = blockIdx.x;         // 0..31
  const int b = bh >> 4;
  const int h = bh & 15;
  const int g = h >> 2;              // GQA group (gs = 4)
  const int q0 = blockIdx.y * 32;
  const int r = tid >> 3;            // query row in tile
  const int e = tid & 7;             // lane-in-row

  // Stage Q tile: 8 threads/row, 16 floats (4 float4) each.
  {
    const int lr = tid >> 3;
    const int lc = (tid & 7) * 16;
    const float* src = q + ((size_t)(b * SEQ + q0 + lr) * NHQ + h) * 128 + lc;
    float4* dst = (float4*)&qs[lr][lc];
    const float4* s4 = (const float4*)src;
    dst[0] = s4[0]; dst[1] = s4[1]; dst[2] = s4[2]; dst[3] = s4[3];
  }

  float mrow = -INFINITY;
  float lsum = 0.0f;
  float acc[16];
#pragma unroll
  for (int i = 0; i < 16; i++) acc[i] = 0.0f;
  const float inv_scale = 1.0f / 16384.0f;

  for (int j0 = 0; j0 <= q0; j0 += 32) {
    // Stage K/V tile.
    {
      const int lr = tid >> 3;
      const int lc = (tid & 7) * 16;
      const float* ksrc = k + ((size_t)(b * SEQ + j0 + lr) * NHK + g) * 128 + lc;
      const float* vsrc = v + ((size_t)(b * SEQ + j0 + lr) * NHK + g) * 128 + lc;
      float4* kd = (float4*)&ks[lr][lc];
      float4* vd = (float4*)&vs[lr][lc];
      const float4* k4 = (const float4*)ksrc;
      const float4* v4 = (const float4*)vsrc;
      kd[0] = k4[0]; kd[1] = k4[1]; kd[2] = k4[2]; kd[3] = k4[3];
      vd[0] = v4[0]; vd[1] = v4[1]; vd[2] = v4[2]; vd[3] = v4[3];
    }
    __syncthreads();

    // QK^T for my 4 keys (kj = jj*8 + e).
    float s[4] = {0.f, 0.f, 0.f, 0.f};
#pragma unroll
    for (int d4 = 0; d4 < 32; ++d4) {
      const float4 qv = *(const float4*)&qs[r][d4 * 4];
#pragma unroll
      for (int jj = 0; jj < 4; ++jj) {
        const float4 kv = *(const float4*)&ks[jj * 8 + e][d4 * 4];
        s[jj] += qv.x * kv.x + qv.y * kv.y + qv.z * kv.z + qv.w * kv.w;
      }
    }
    float tmax = -INFINITY;
#pragma unroll
    for (int jj = 0; jj < 4; ++jj) {
      const int kg = j0 + jj * 8 + e;
      s[jj] = (kg > q0 + r) ? -INFINITY : s[jj] * inv_scale;
      tmax = fmaxf(tmax, s[jj]);
    }
    tmax = fmaxf(tmax, __shfl_xor(tmax, 1));
    tmax = fmaxf(tmax, __shfl_xor(tmax, 2));
    tmax = fmaxf(tmax, __shfl_xor(tmax, 4));
    const float mnew = fmaxf(mrow, tmax);
    const float alpha = expf(mrow - mnew);  // first tile: exp(-inf)=0, safe
    float p[4];
    float psum = 0.0f;
#pragma unroll
    for (int jj = 0; jj < 4; ++jj) {
      p[jj] = expf(s[jj] - mnew);           // masked: exp(-inf)=0
      psum += p[jj];
    }
    psum += __shfl_xor(psum, 1);
    psum += __shfl_xor(psum, 2);
    psum += __shfl_xor(psum, 4);
    lsum = lsum * alpha + psum;
    mrow = mnew;
#pragma unroll
    for (int jj = 0; jj < 4; ++jj) ps[r][jj * 8 + e] = p[jj];
#pragma unroll
    for (int i = 0; i < 16; i++) acc[i] *= alpha;
    __syncthreads();

    // PV: my 16 dims are chunks c = e + 8*i (bank-uniform float4s).
    for (int kj = 0; kj < 32; ++kj) {
      const float pv = ps[r][kj];
#pragma unroll
      for (int i = 0; i < 4; ++i) {
        const float4 vv = *(const float4*)&vs[kj][4 * (e + 8 * i)];
        acc[4 * i + 0] += pv * vv.x;
        acc[4 * i + 1] += pv * vv.y;
        acc[4 * i + 2] += pv * vv.z;
        acc[4 * i + 3] += pv * vv.w;
      }
    }
    __syncthreads();
  }

  const float invl = 1.0f / lsum;
  float* dst = o + ((size_t)(b * SEQ + q0 + r) * NHQ + h) * 128;
#pragma unroll
  for (int i = 0; i < 4; ++i) {
    const int c = e + 8 * i;
    float4 w;
    w.x = acc[4 * i + 0] * invl;
    w.y = acc[4 * i + 1] * invl;
    w.z = acc[4 * i + 2] * invl;
    w.w = acc[4 * i + 3] * invl;
    *(float4*)(dst + 4 * c) = w;
  }
}

// ---------------------------------------------------------------------------
extern "C" void kernel_launch(void* const* d_in, const int* in_sizes, int n_in,
                              void* d_out, int out_size, void* d_ws, size_t ws_size,
                              hipStream_t stream) {
  const float* x       = (const float*)d_in[0];  // (4096, 2048)
  const float* Wq      = (const float*)d_in[1];  // (2048, 2048)
  const float* Wk      = (const float*)d_in[2];  // (2048, 512)
  const float* Wv      = (const float*)d_in[3];  // (2048, 512)
  const float* Wo      = (const float*)d_in[4];  // (2048, 2048)
  const float* q_scale = (const float*)d_in[5];  // (128)
  const float* k_scale = (const float*)d_in[6];  // (128)
  const float* cosb    = (const float*)d_in[7];  // (2048, 128)
  const float* sinb    = (const float*)d_in[8];  // (2048, 128)
  // d_in[9] = mask, unused (causal triu k=1, hard-coded)
  float* out = (float*)d_out;                    // (4096, 2048)

  float* ws = (float*)d_ws;
  float* q    = ws;                              // 4096*2048
  float* kbuf = q + (size_t)4096 * 2048;         // 4096*512
  float* vbuf = kbuf + (size_t)4096 * 512;       // 4096*512
  float* attn = vbuf + (size_t)4096 * 512;       // 4096*2048  (total ~80 MiB)

  // QKV projections.
  gemm_f32<<<dim3(2048 / 128, 4096 / 128), 256, 0, stream>>>(x, Wq, q, 4096, 2048, 2048);
  gemm_f32<<<dim3(512 / 128, 4096 / 128), 256, 0, stream>>>(x, Wk, kbuf, 4096, 512, 2048);
  gemm_f32<<<dim3(512 / 128, 4096 / 128), 256, 0, stream>>>(x, Wv, vbuf, 4096, 512, 2048);

  // RMSNorm + RoPE (in place).
  rmsnorm_rope<<<dim3(4096, NHQ / 4), dim3(64, 4), 0, stream>>>(q, NHQ, q_scale, cosb, sinb);
  rmsnorm_rope<<<dim3(4096, NHK / 4), dim3(64, 4), 0, stream>>>(kbuf, NHK, k_scale, cosb, sinb);

  // Causal GQA attention.
  attention<<<dim3(32, SEQ / 32), 256, 0, stream>>>(q, kbuf, vbuf, attn);

  // Output projection.
  gemm_f32<<<dim3(2048 / 128, 4096 / 128), 256, 0, stream>>>(attn, Wo, out, 4096, 2048, 2048);
}

// Round 2
// 1698.491 us; speedup vs baseline: 1.6748x; 1.6748x over previous
//
#include <hip/hip_runtime.h>
#include <math.h>

// Problem constants (fixed by reference):
// B=2, L=2048, D=2048, H=16, G=4, HD=128, EPS=1e-6, scale = 1/HD^2 = 1/16384
#define SEQ 2048
#define DMODEL 2048
#define NHQ 16
#define NHK 4

typedef __attribute__((ext_vector_type(8))) short short8;
typedef __attribute__((ext_vector_type(4))) float floatx4;

__device__ __forceinline__ unsigned short f2bf(float f) {
  unsigned int u = __builtin_bit_cast(unsigned int, f);
  u += 0x7fffu + ((u >> 16) & 1u);   // round-to-nearest-even
  return (unsigned short)(u >> 16);
}

// ---------------------------------------------------------------------------
// cast fp32 -> bf16, 4 elements/thread.
// ---------------------------------------------------------------------------
__global__ __launch_bounds__(256) void cast_bf16(const float* __restrict__ in,
                                                 unsigned short* __restrict__ out) {
  const size_t i = ((size_t)blockIdx.x * 256 + threadIdx.x) * 4;
  const float4 v = *(const float4*)(in + i);
  ushort4 w;
  w.x = f2bf(v.x); w.y = f2bf(v.y); w.z = f2bf(v.z); w.w = f2bf(v.w);
  *(ushort4*)(out + i) = w;
}

// ---------------------------------------------------------------------------
// transpose + cast: in fp32 [R][C] -> out bf16 [C][R]. 32x32 LDS tile.
// block (32,8), grid (C/32, R/32).
// ---------------------------------------------------------------------------
__global__ __launch_bounds__(256) void transpose_cast(const float* __restrict__ in,
                                                      unsigned short* __restrict__ out,
                                                      int R, int C) {
  __shared__ float tile[32][33];
  const int tx = threadIdx.x, ty = threadIdx.y;
  const int c0 = blockIdx.x * 32, r0 = blockIdx.y * 32;
#pragma unroll
  for (int j = 0; j < 4; ++j)
    tile[ty + j * 8][tx] = in[(size_t)(r0 + ty + j * 8) * C + c0 + tx];
  __syncthreads();
#pragma unroll
  for (int j = 0; j < 4; ++j)
    out[(size_t)(c0 + ty + j * 8) * R + r0 + tx] = f2bf(tile[tx][ty + j * 8]);
}

// ---------------------------------------------------------------------------
// bf16 MFMA GEMM (m97 structure): C[M][N] = A[M][K] @ B[K][N], fp32 out.
// A row-major bf16, Bt = B^T row-major bf16 ([N][K]).
// 256 threads = 4 waves; 128x128 tile; BK=32; wave -> 64x64 subtile,
// 4x4 grid of 16x16x32 MFMA tiles. global_load_lds width-16 staging.
// M,N % 128 == 0, K % 32 == 0.
// ---------------------------------------------------------------------------
__global__ __launch_bounds__(256) void gemm_bf16(const unsigned short* __restrict__ A,
                                                 const unsigned short* __restrict__ Bt,
                                                 float* __restrict__ C,
                                                 int M, int N, int K) {
  __shared__ unsigned short As[128 * 32];
  __shared__ unsigned short Bs[128 * 32];
  const int tid = threadIdx.x;
  const int wave = tid >> 6;
  const int lane = tid & 63;
  const int bm = blockIdx.y * 128;
  const int bn = blockIdx.x * 128;
  const int wr = wave >> 1;      // 0..1 (M half)
  const int wc = wave & 1;       // 0..1 (N half)
  const int m15 = lane & 15;
  const int quad = lane >> 4;

  floatx4 acc[4][4];
#pragma unroll
  for (int i = 0; i < 4; ++i)
#pragma unroll
    for (int j = 0; j < 4; ++j) acc[i][j] = (floatx4){0.f, 0.f, 0.f, 0.f};

  // staging: each wave stages 32 rows (2 iters x 16 rows) of each tile.
  const int srow = lane >> 2;           // 0..15 row within 16-row slab
  const int scol = (lane & 3) * 8;      // k-chunk (8 bf16 = 16 B)

  for (int k0 = 0; k0 < K; k0 += 32) {
#pragma unroll
    for (int it = 0; it < 2; ++it) {
      const int rowa = wave * 32 + it * 16;
      const unsigned short* ga = A + (size_t)(bm + rowa + srow) * K + k0 + scol;
      const unsigned short* gb = Bt + (size_t)(bn + rowa + srow) * K + k0 + scol;
      __builtin_amdgcn_global_load_lds(
          (const __attribute__((address_space(1))) void*)ga,
          (__attribute__((address_space(3))) void*)&As[rowa * 32], 16, 0, 0);
      __builtin_amdgcn_global_load_lds(
          (const __attribute__((address_space(1))) void*)gb,
          (__attribute__((address_space(3))) void*)&Bs[rowa * 32], 16, 0, 0);
    }
    __syncthreads();

    short8 af[4], bfr[4];
    const unsigned short* pa = &As[(wr * 64 + m15) * 32 + quad * 8];
    const unsigned short* pb = &Bs[(wc * 64 + m15) * 32 + quad * 8];
#pragma unroll
    for (int i = 0; i < 4; ++i) af[i] = *(const short8*)(pa + i * 16 * 32);
#pragma unroll
    for (int j = 0; j < 4; ++j) bfr[j] = *(const short8*)(pb + j * 16 * 32);
#pragma unroll
    for (int i = 0; i < 4; ++i)
#pragma unroll
      for (int j = 0; j < 4; ++j)
        acc[i][j] = __builtin_amdgcn_mfma_f32_16x16x32_bf16(af[i], bfr[j], acc[i][j], 0, 0, 0);
    __syncthreads();
  }

  // Epilogue: C/D layout col = lane&15, row = quad*4 + reg.
#pragma unroll
  for (int i = 0; i < 4; ++i)
#pragma unroll
    for (int j = 0; j < 4; ++j) {
      const int col = bn + wc * 64 + j * 16 + m15;
#pragma unroll
      for (int reg = 0; reg < 4; ++reg) {
        const int row = bm + wr * 64 + i * 16 + quad * 4 + reg;
        C[(size_t)row * N + col] = acc[i][j][reg];
      }
    }
}

// ---------------------------------------------------------------------------
// Fused RMSNorm (over HD=128 per head) + RoPE, in place (fp32).
// ---------------------------------------------------------------------------
__global__ __launch_bounds__(256) void rmsnorm_rope(float* __restrict__ buf, int NH,
                                                    const float* __restrict__ scale,
                                                    const float* __restrict__ cosb,
                                                    const float* __restrict__ sinb) {
  const int t = threadIdx.x;                       // 0..63
  const int head = blockIdx.y * 4 + threadIdx.y;   // grid.y = NH/4
  const int row = blockIdx.x;                      // 0..B*L-1
  const int l = row & (SEQ - 1);
  float* base = buf + ((size_t)row * NH + head) * 128;
  float v0 = base[t];
  float v1 = base[t + 64];
  float ss = v0 * v0 + v1 * v1;
#pragma unroll
  for (int m = 1; m < 64; m <<= 1) ss += __shfl_xor(ss, m);
  const float r = rsqrtf(ss * (1.0f / 128.0f) + 1e-6f);
  const float a0 = v0 * r * scale[t];
  const float a1 = v1 * r * scale[t + 64];
  const float c0 = cosb[(size_t)l * 128 + t];
  const float s0 = sinb[(size_t)l * 128 + t];
  const float c1 = cosb[(size_t)l * 128 + t + 64];
  const float s1 = sinb[(size_t)l * 128 + t + 64];
  base[t]      = a0 * c0 - a1 * s0;
  base[t + 64] = a1 * c1 + a0 * s1;
}

// ---------------------------------------------------------------------------
// Causal GQA attention (fp32 compute), bf16 output.
// ---------------------------------------------------------------------------
__global__ __launch_bounds__(256) void attention(const float* __restrict__ q,
                                                 const float* __restrict__ k,
                                                 const float* __restrict__ v,
                                                 unsigned short* __restrict__ o) {
  __shared__ float qs[32][132];
  __shared__ float ks[32][132];
  __shared__ float vs[32][132];
  __shared__ float ps[32][33];

  const int tid = threadIdx.x;
  const int bh = blockIdx.x;         // 0..31
  const int b = bh >> 4;
  const int h = bh & 15;
  const int g = h >> 2;              // GQA group (gs = 4)
  const int q0 = blockIdx.y * 32;
  const int r = tid >> 3;
  const int e = tid & 7;

  {
    const int lr = tid >> 3;
    const int lc = (tid & 7) * 16;
    const float* src = q + ((size_t)(b * SEQ + q0 + lr) * NHQ + h) * 128 + lc;
    float4* dst = (float4*)&qs[lr][lc];
    const float4* s4 = (const float4*)src;
    dst[0] = s4[0]; dst[1] = s4[1]; dst[2] = s4[2]; dst[3] = s4[3];
  }

  float mrow = -INFINITY;
  float lsum = 0.0f;
  float acc[16];
#pragma unroll
  for (int i = 0; i < 16; i++) acc[i] = 0.0f;
  const float inv_scale = 1.0f / 16384.0f;

  for (int j0 = 0; j0 <= q0; j0 += 32) {
    {
      const int lr = tid >> 3;
      const int lc = (tid & 7) * 16;
      const float* ksrc = k + ((size_t)(b * SEQ + j0 + lr) * NHK + g) * 128 + lc;
      const float* vsrc = v + ((size_t)(b * SEQ + j0 + lr) * NHK + g) * 128 + lc;
      float4* kd = (float4*)&ks[lr][lc];
      float4* vd = (float4*)&vs[lr][lc];
      const float4* k4 = (const float4*)ksrc;
      const float4* v4 = (const float4*)vsrc;
      kd[0] = k4[0]; kd[1] = k4[1]; kd[2] = k4[2]; kd[3] = k4[3];
      vd[0] = v4[0]; vd[1] = v4[1]; vd[2] = v4[2]; vd[3] = v4[3];
    }
    __syncthreads();

    float s[4] = {0.f, 0.f, 0.f, 0.f};
#pragma unroll
    for (int d4 = 0; d4 < 32; ++d4) {
      const float4 qv = *(const float4*)&qs[r][d4 * 4];
#pragma unroll
      for (int jj = 0; jj < 4; ++jj) {
        const float4 kv = *(const float4*)&ks[jj * 8 + e][d4 * 4];
        s[jj] += qv.x * kv.x + qv.y * kv.y + qv.z * kv.z + qv.w * kv.w;
      }
    }
    float tmax = -INFINITY;
#pragma unroll
    for (int jj = 0; jj < 4; ++jj) {
      const int kg = j0 + jj * 8 + e;
      s[jj] = (kg > q0 + r) ? -INFINITY : s[jj] * inv_scale;
      tmax = fmaxf(tmax, s[jj]);
    }
    tmax = fmaxf(tmax, __shfl_xor(tmax, 1));
    tmax = fmaxf(tmax, __shfl_xor(tmax, 2));
    tmax = fmaxf(tmax, __shfl_xor(tmax, 4));
    const float mnew = fmaxf(mrow, tmax);
    const float alpha = expf(mrow - mnew);
    float p[4];
    float psum = 0.0f;
#pragma unroll
    for (int jj = 0; jj < 4; ++jj) {
      p[jj] = expf(s[jj] - mnew);
      psum += p[jj];
    }
    psum += __shfl_xor(psum, 1);
    psum += __shfl_xor(psum, 2);
    psum += __shfl_xor(psum, 4);
    lsum = lsum * alpha + psum;
    mrow = mnew;
#pragma unroll
    for (int jj = 0; jj < 4; ++jj) ps[r][jj * 8 + e] = p[jj];
#pragma unroll
    for (int i = 0; i < 16; i++) acc[i] *= alpha;
    __syncthreads();

    for (int kj = 0; kj < 32; ++kj) {
      const float pv = ps[r][kj];
#pragma unroll
      for (int i = 0; i < 4; ++i) {
        const float4 vv = *(const float4*)&vs[kj][4 * (e + 8 * i)];
        acc[4 * i + 0] += pv * vv.x;
        acc[4 * i + 1] += pv * vv.y;
        acc[4 * i + 2] += pv * vv.z;
        acc[4 * i + 3] += pv * vv.w;
      }
    }
    __syncthreads();
  }

  const float invl = 1.0f / lsum;
  unsigned short* dst = o + ((size_t)(b * SEQ + q0 + r) * NHQ + h) * 128;
#pragma unroll
  for (int i = 0; i < 4; ++i) {
    const int c = e + 8 * i;
    ushort4 w;
    w.x = f2bf(acc[4 * i + 0] * invl);
    w.y = f2bf(acc[4 * i + 1] * invl);
    w.z = f2bf(acc[4 * i + 2] * invl);
    w.w = f2bf(acc[4 * i + 3] * invl);
    *(ushort4*)(dst + 4 * c) = w;
  }
}

// ---------------------------------------------------------------------------
extern "C" void kernel_launch(void* const* d_in, const int* in_sizes, int n_in,
                              void* d_out, int out_size, void* d_ws, size_t ws_size,
                              hipStream_t stream) {
  const float* x       = (const float*)d_in[0];  // (4096, 2048)
  const float* Wq      = (const float*)d_in[1];  // (2048, 2048)
  const float* Wk      = (const float*)d_in[2];  // (2048, 512)
  const float* Wv      = (const float*)d_in[3];  // (2048, 512)
  const float* Wo      = (const float*)d_in[4];  // (2048, 2048)
  const float* q_scale = (const float*)d_in[5];  // (128)
  const float* k_scale = (const float*)d_in[6];  // (128)
  const float* cosb    = (const float*)d_in[7];  // (2048, 128)
  const float* sinb    = (const float*)d_in[8];  // (2048, 128)
  float* out = (float*)d_out;                    // (4096, 2048)

  // Workspace layout (79.7 MB total; round 1 proved >= 84 MB available):
  char* w = (char*)d_ws;
  unsigned short* x_bf = (unsigned short*)w;                  // 16.78 MB
  float* q             = (float*)(w + 16777216);              // 33.55 MB
  float* kbuf          = (float*)(w + 50331648);              //  8.39 MB
  float* vbuf          = (float*)(w + 58720256);              //  8.39 MB
  unsigned short* wq_t = (unsigned short*)(w + 67108864);     //  8.39 MB
  unsigned short* wk_t = (unsigned short*)(w + 75497472);     //  2.10 MB
  unsigned short* wv_t = (unsigned short*)(w + 77594624);     //  2.10 MB
  unsigned short* attn_bf = x_bf;   // overlay: x_bf dead after V GEMM
  unsigned short* wo_t    = wq_t;   // overlay: wq_t dead after Q GEMM

  // Pre-pass: casts + weight transposes (Wo's runs later, overlaying wq_t).
  cast_bf16<<<(4096 * 2048 / 4) / 256, 256, 0, stream>>>(x, x_bf);
  transpose_cast<<<dim3(2048 / 32, 2048 / 32), dim3(32, 8), 0, stream>>>(Wq, wq_t, 2048, 2048);
  transpose_cast<<<dim3(512 / 32, 2048 / 32), dim3(32, 8), 0, stream>>>(Wk, wk_t, 2048, 512);
  transpose_cast<<<dim3(512 / 32, 2048 / 32), dim3(32, 8), 0, stream>>>(Wv, wv_t, 2048, 512);

  // QKV projections (bf16 MFMA, fp32 out).
  gemm_bf16<<<dim3(2048 / 128, 4096 / 128), 256, 0, stream>>>(x_bf, wq_t, q, 4096, 2048, 2048);
  gemm_bf16<<<dim3(512 / 128, 4096 / 128), 256, 0, stream>>>(x_bf, wk_t, kbuf, 4096, 512, 2048);
  gemm_bf16<<<dim3(512 / 128, 4096 / 128), 256, 0, stream>>>(x_bf, wv_t, vbuf, 4096, 512, 2048);

  // RMSNorm + RoPE (in place, fp32).
  rmsnorm_rope<<<dim3(4096, NHQ / 4), dim3(64, 4), 0, stream>>>(q, NHQ, q_scale, cosb, sinb);
  rmsnorm_rope<<<dim3(4096, NHK / 4), dim3(64, 4), 0, stream>>>(kbuf, NHK, k_scale, cosb, sinb);

  // Causal GQA attention -> bf16.
  attention<<<dim3(32, SEQ / 32), 256, 0, stream>>>(q, kbuf, vbuf, attn_bf);

  // Output projection.
  transpose_cast<<<dim3(2048 / 32, 2048 / 32), dim3(32, 8), 0, stream>>>(Wo, wo_t, 2048, 2048);
  gemm_bf16<<<dim3(2048 / 128, 4096 / 128), 256, 0, stream>>>(attn_bf, wo_t, out, 4096, 2048, 2048);
}

// Round 3
// 477.802 us; speedup vs baseline: 5.9537x; 3.5548x over previous
//
#include <hip/hip_runtime.h>
#include <math.h>

// Problem constants (fixed by reference):
// B=2, L=2048, D=2048, H=16, G=4, HD=128, EPS=1e-6, scale = 1/HD^2 = 1/16384
#define SEQ 2048
#define DMODEL 2048
#define NHQ 16
#define NHK 4

typedef __attribute__((ext_vector_type(8))) short short8;
typedef __attribute__((ext_vector_type(4))) float floatx4;
typedef unsigned short ushort_t;

__device__ __forceinline__ unsigned short f2bf(float f) {
  unsigned int u = __builtin_bit_cast(unsigned int, f);
  u += 0x7fffu + ((u >> 16) & 1u);   // round-to-nearest-even
  return (unsigned short)(u >> 16);
}

// ---------------------------------------------------------------------------
// cast fp32 -> bf16, 4 elements/thread.
// ---------------------------------------------------------------------------
__global__ __launch_bounds__(256) void cast_bf16(const float* __restrict__ in,
                                                 unsigned short* __restrict__ out) {
  const size_t i = ((size_t)blockIdx.x * 256 + threadIdx.x) * 4;
  const float4 v = *(const float4*)(in + i);
  ushort4 w;
  w.x = f2bf(v.x); w.y = f2bf(v.y); w.z = f2bf(v.z); w.w = f2bf(v.w);
  *(ushort4*)(out + i) = w;
}

// ---------------------------------------------------------------------------
// transpose + cast: in fp32 [R][C] -> out bf16 [C][R]. 32x32 LDS tile.
// ---------------------------------------------------------------------------
__global__ __launch_bounds__(256) void transpose_cast(const float* __restrict__ in,
                                                      unsigned short* __restrict__ out,
                                                      int R, int C) {
  __shared__ float tile[32][33];
  const int tx = threadIdx.x, ty = threadIdx.y;
  const int c0 = blockIdx.x * 32, r0 = blockIdx.y * 32;
#pragma unroll
  for (int j = 0; j < 4; ++j)
    tile[ty + j * 8][tx] = in[(size_t)(r0 + ty + j * 8) * C + c0 + tx];
  __syncthreads();
#pragma unroll
  for (int j = 0; j < 4; ++j)
    out[(size_t)(c0 + ty + j * 8) * R + r0 + tx] = f2bf(tile[tx][ty + j * 8]);
}

// ---------------------------------------------------------------------------
// V transpose: v fp32 [b*L][G][128] -> vt bf16 [(b*G+g)][128][L].
// block (32,8), grid (L/32, 128/32, B*G).
// ---------------------------------------------------------------------------
__global__ __launch_bounds__(256) void transpose_v(const float* __restrict__ in,
                                                   unsigned short* __restrict__ out) {
  __shared__ float tile[32][33];
  const int tx = threadIdx.x, ty = threadIdx.y;
  const int l0 = blockIdx.x * 32, d0 = blockIdx.y * 32;
  const int bg = blockIdx.z;                 // b*4+g
  const int b = bg >> 2, g = bg & 3;
#pragma unroll
  for (int j = 0; j < 4; ++j)
    tile[ty + j * 8][tx] = in[(size_t)(b * SEQ + l0 + ty + j * 8) * (NHK * 128) + g * 128 + d0 + tx];
  __syncthreads();
#pragma unroll
  for (int j = 0; j < 4; ++j)
    out[((size_t)bg * 128 + d0 + ty + j * 8) * SEQ + l0 + tx] = f2bf(tile[tx][ty + j * 8]);
}

// ---------------------------------------------------------------------------
// bf16 MFMA GEMM (m97 structure): C[M][N] = A[M][K] @ B[K][N], fp32 out.
// ---------------------------------------------------------------------------
__global__ __launch_bounds__(256) void gemm_bf16(const unsigned short* __restrict__ A,
                                                 const unsigned short* __restrict__ Bt,
                                                 float* __restrict__ C,
                                                 int M, int N, int K) {
  __shared__ unsigned short As[128 * 32];
  __shared__ unsigned short Bs[128 * 32];
  const int tid = threadIdx.x;
  const int wave = tid >> 6;
  const int lane = tid & 63;
  const int bm = blockIdx.y * 128;
  const int bn = blockIdx.x * 128;
  const int wr = wave >> 1;
  const int wc = wave & 1;
  const int m15 = lane & 15;
  const int quad = lane >> 4;

  floatx4 acc[4][4];
#pragma unroll
  for (int i = 0; i < 4; ++i)
#pragma unroll
    for (int j = 0; j < 4; ++j) acc[i][j] = (floatx4){0.f, 0.f, 0.f, 0.f};

  const int srow = lane >> 2;
  const int scol = (lane & 3) * 8;

  for (int k0 = 0; k0 < K; k0 += 32) {
#pragma unroll
    for (int it = 0; it < 2; ++it) {
      const int rowa = wave * 32 + it * 16;
      const unsigned short* ga = A + (size_t)(bm + rowa + srow) * K + k0 + scol;
      const unsigned short* gb = Bt + (size_t)(bn + rowa + srow) * K + k0 + scol;
      __builtin_amdgcn_global_load_lds(
          (const __attribute__((address_space(1))) void*)ga,
          (__attribute__((address_space(3))) void*)&As[rowa * 32], 16, 0, 0);
      __builtin_amdgcn_global_load_lds(
          (const __attribute__((address_space(1))) void*)gb,
          (__attribute__((address_space(3))) void*)&Bs[rowa * 32], 16, 0, 0);
    }
    __syncthreads();

    short8 af[4], bfr[4];
    const unsigned short* pa = &As[(wr * 64 + m15) * 32 + quad * 8];
    const unsigned short* pb = &Bs[(wc * 64 + m15) * 32 + quad * 8];
#pragma unroll
    for (int i = 0; i < 4; ++i) af[i] = *(const short8*)(pa + i * 16 * 32);
#pragma unroll
    for (int j = 0; j < 4; ++j) bfr[j] = *(const short8*)(pb + j * 16 * 32);
#pragma unroll
    for (int i = 0; i < 4; ++i)
#pragma unroll
      for (int j = 0; j < 4; ++j)
        acc[i][j] = __builtin_amdgcn_mfma_f32_16x16x32_bf16(af[i], bfr[j], acc[i][j], 0, 0, 0);
    __syncthreads();
  }

#pragma unroll
  for (int i = 0; i < 4; ++i)
#pragma unroll
    for (int j = 0; j < 4; ++j) {
      const int col = bn + wc * 64 + j * 16 + m15;
#pragma unroll
      for (int reg = 0; reg < 4; ++reg) {
        const int row = bm + wr * 64 + i * 16 + quad * 4 + reg;
        C[(size_t)row * N + col] = acc[i][j][reg];
      }
    }
}

// ---------------------------------------------------------------------------
// Fused RMSNorm + RoPE: fp32 in [row][NH][128] -> bf16 out [(b*NH+h)][l][128].
// ---------------------------------------------------------------------------
__global__ __launch_bounds__(256) void rmsnorm_rope(const float* __restrict__ in,
                                                    unsigned short* __restrict__ out, int NH,
                                                    const float* __restrict__ scale,
                                                    const float* __restrict__ cosb,
                                                    const float* __restrict__ sinb) {
  const int t = threadIdx.x;                       // 0..63
  const int head = blockIdx.y * 4 + threadIdx.y;
  const int row = blockIdx.x;                      // 0..B*L-1
  const int b = row >> 11;
  const int l = row & (SEQ - 1);
  const float* base = in + ((size_t)row * NH + head) * 128;
  float v0 = base[t];
  float v1 = base[t + 64];
  float ss = v0 * v0 + v1 * v1;
#pragma unroll
  for (int m = 1; m < 64; m <<= 1) ss += __shfl_xor(ss, m);
  const float r = rsqrtf(ss * (1.0f / 128.0f) + 1e-6f);
  const float a0 = v0 * r * scale[t];
  const float a1 = v1 * r * scale[t + 64];
  const float c0 = cosb[(size_t)l * 128 + t];
  const float s0 = sinb[(size_t)l * 128 + t];
  const float c1 = cosb[(size_t)l * 128 + t + 64];
  const float s1 = sinb[(size_t)l * 128 + t + 64];
  unsigned short* dst = out + ((size_t)(b * NH + head) * SEQ + l) * 128;
  dst[t]      = f2bf(a0 * c0 - a1 * s0);
  dst[t + 64] = f2bf(a1 * c1 + a0 * s1);
}

// ---------------------------------------------------------------------------
// MFMA flash attention (causal GQA). bf16 in/out, fp32 accumulate.
// Grid (B*H, L/64), 256 threads = 4 waves. Wave w: query rows [w*16, w*16+16).
// q: [(b*H+h)][l][128], k: [(b*G+g)][l][128], vt: [(b*G+g)][d][l] (all bf16).
// Q/K LDS tiles: row-major, chunk-XOR-swizzled (chunk=8 bf16, c_lds=c^ (r&15)).
// Vt LDS tile: [128][64], c_lds = c ^ (d&7). P: [64][72] padded, unswizzled.
// ---------------------------------------------------------------------------
__global__ __launch_bounds__(256) void attn_mfma(const unsigned short* __restrict__ qb,
                                                 const unsigned short* __restrict__ kb,
                                                 const unsigned short* __restrict__ vtb,
                                                 unsigned short* __restrict__ o) {
  __shared__ unsigned short Qs[64 * 128];
  __shared__ unsigned short Ks[64 * 128];
  __shared__ unsigned short Vs[128 * 64];
  __shared__ unsigned short Ps[64 * 72];

  const int tid = threadIdx.x;
  const int wave = tid >> 6;
  const int lane = tid & 63;
  const int m15 = lane & 15;
  const int quad = lane >> 4;
  const int bh = blockIdx.x;           // 0..31
  const int b = bh >> 4;
  const int h = bh & 15;
  const int g = h >> 2;
  const int q0 = blockIdx.y * 64;

  const unsigned short* qhead = qb + (size_t)bh * SEQ * 128;
  const unsigned short* khead = kb + (size_t)(b * NHK + g) * SEQ * 128;
  const unsigned short* vthead = vtb + (size_t)(b * NHK + g) * 128 * SEQ;

  // ---- stage Q tile (64 rows x 128), swizzled; wave w stages rows w*16..+15
#pragma unroll
  for (int t = 0; t < 4; ++t) {
    const int r = wave * 16 + t * 4 + (lane >> 4);          // local row
    const int cg = (lane & 15) ^ (r & 15);                  // global chunk
    const unsigned short* src = qhead + (size_t)(q0 + r) * 128 + cg * 8;
    __builtin_amdgcn_global_load_lds(
        (const __attribute__((address_space(1))) void*)src,
        (__attribute__((address_space(3))) void*)&Qs[(wave * 16 + t * 4) * 128], 16, 0, 0);
  }

  floatx4 acc_o[8];
#pragma unroll
  for (int n = 0; n < 8; ++n) acc_o[n] = (floatx4){0.f, 0.f, 0.f, 0.f};
  float m_run[4], l_run[4];
#pragma unroll
  for (int rg = 0; rg < 4; ++rg) { m_run[rg] = -INFINITY; l_run[rg] = 0.0f; }
  const float inv_scale = 1.0f / 16384.0f;

  for (int j0 = 0; j0 <= q0; j0 += 64) {
    // ---- stage K tile (64 x 128), same pattern as Q
#pragma unroll
    for (int t = 0; t < 4; ++t) {
      const int r = wave * 16 + t * 4 + (lane >> 4);
      const int cg = (lane & 15) ^ (r & 15);
      const unsigned short* src = khead + (size_t)(j0 + r) * 128 + cg * 8;
      __builtin_amdgcn_global_load_lds(
          (const __attribute__((address_space(1))) void*)src,
          (__attribute__((address_space(3))) void*)&Ks[(wave * 16 + t * 4) * 128], 16, 0, 0);
    }
    // ---- stage Vt tile (128 dims x 64 keys), rows of 8 chunks
#pragma unroll
    for (int t = 0; t < 4; ++t) {
      const int d = wave * 32 + t * 8 + (lane >> 3);
      const int cg = (lane & 7) ^ (d & 7);
      const unsigned short* src = vthead + (size_t)d * SEQ + j0 + cg * 8;
      __builtin_amdgcn_global_load_lds(
          (const __attribute__((address_space(1))) void*)src,
          (__attribute__((address_space(3))) void*)&Vs[(wave * 32 + t * 8) * 64], 16, 0, 0);
    }
    __syncthreads();

    // ---- S = Q K^T  (wave rows w*16..+15, all 64 keys)
    floatx4 acc_s[4];
#pragma unroll
    for (int n = 0; n < 4; ++n) acc_s[n] = (floatx4){0.f, 0.f, 0.f, 0.f};
#pragma unroll
    for (int ks = 0; ks < 4; ++ks) {
      const int qrow = wave * 16 + m15;
      const short8 a = *(const short8*)&Qs[qrow * 128 + (((ks * 4 + quad) ^ m15) * 8)];
#pragma unroll
      for (int n = 0; n < 4; ++n) {
        const int krow = n * 16 + m15;
        const short8 bfrag = *(const short8*)&Ks[krow * 128 + (((ks * 4 + quad) ^ m15) * 8)];
        acc_s[n] = __builtin_amdgcn_mfma_f32_16x16x32_bf16(a, bfrag, acc_s[n], 0, 0, 0);
      }
    }

    // ---- mask + online softmax (rows = quad*4+reg, cols = n*16+m15)
    const int qrow_g = q0 + wave * 16 + quad * 4;   // + reg
    float p[4][4];                                   // [n][reg]
    float mx[4];
#pragma unroll
    for (int rg = 0; rg < 4; ++rg) mx[rg] = -INFINITY;
#pragma unroll
    for (int n = 0; n < 4; ++n) {
      const int col = j0 + n * 16 + m15;
#pragma unroll
      for (int rg = 0; rg < 4; ++rg) {
        float s = (col > qrow_g + rg) ? -INFINITY : acc_s[n][rg] * inv_scale;
        p[n][rg] = s;
        mx[rg] = fmaxf(mx[rg], s);
      }
    }
#pragma unroll
    for (int rg = 0; rg < 4; ++rg) {
      mx[rg] = fmaxf(mx[rg], __shfl_xor(mx[rg], 1));
      mx[rg] = fmaxf(mx[rg], __shfl_xor(mx[rg], 2));
      mx[rg] = fmaxf(mx[rg], __shfl_xor(mx[rg], 4));
      mx[rg] = fmaxf(mx[rg], __shfl_xor(mx[rg], 8));
    }
    float alpha[4], rsum[4];
#pragma unroll
    for (int rg = 0; rg < 4; ++rg) {
      const float mnew = fmaxf(m_run[rg], mx[rg]);
      alpha[rg] = __expf(m_run[rg] - mnew);
      m_run[rg] = mnew;
      rsum[rg] = 0.0f;
#pragma unroll
      for (int n = 0; n < 4; ++n) {
        const float e = __expf(p[n][rg] - mnew);
        p[n][rg] = e;
        rsum[rg] += e;
      }
    }
#pragma unroll
    for (int rg = 0; rg < 4; ++rg) {
      rsum[rg] += __shfl_xor(rsum[rg], 1);
      rsum[rg] += __shfl_xor(rsum[rg], 2);
      rsum[rg] += __shfl_xor(rsum[rg], 4);
      rsum[rg] += __shfl_xor(rsum[rg], 8);
      l_run[rg] = l_run[rg] * alpha[rg] + rsum[rg];
    }
    // write P to LDS (bf16), rescale O
#pragma unroll
    for (int n = 0; n < 4; ++n)
#pragma unroll
      for (int rg = 0; rg < 4; ++rg)
        Ps[(wave * 16 + quad * 4 + rg) * 72 + n * 16 + m15] = f2bf(p[n][rg]);
#pragma unroll
    for (int n = 0; n < 8; ++n)
#pragma unroll
      for (int rg = 0; rg < 4; ++rg) acc_o[n][rg] *= alpha[rg];

    // ---- O += P V  (A = Ps rows w*16+m15, B = Vt rows n*16+m15)
#pragma unroll
    for (int kk = 0; kk < 2; ++kk) {
      const short8 a = *(const short8*)&Ps[(wave * 16 + m15) * 72 + kk * 32 + quad * 8];
#pragma unroll
      for (int n = 0; n < 8; ++n) {
        const int drow = n * 16 + m15;
        const short8 bfrag = *(const short8*)&Vs[drow * 64 + (((kk * 4 + quad) ^ (m15 & 7)) * 8)];
        acc_o[n] = __builtin_amdgcn_mfma_f32_16x16x32_bf16(a, bfrag, acc_o[n], 0, 0, 0);
      }
    }
    __syncthreads();
  }

  // ---- epilogue: O /= l, write bf16 to attn buffer [b*SEQ+l][H*128]
#pragma unroll
  for (int rg = 0; rg < 4; ++rg) {
    const float invl = 1.0f / l_run[rg];
    const size_t row = (size_t)(b * SEQ + q0 + wave * 16 + quad * 4 + rg);
#pragma unroll
    for (int n = 0; n < 8; ++n)
      o[row * DMODEL + h * 128 + n * 16 + m15] = f2bf(acc_o[n][rg] * invl);
  }
}

// ---------------------------------------------------------------------------
extern "C" void kernel_launch(void* const* d_in, const int* in_sizes, int n_in,
                              void* d_out, int out_size, void* d_ws, size_t ws_size,
                              hipStream_t stream) {
  const float* x       = (const float*)d_in[0];
  const float* Wq      = (const float*)d_in[1];
  const float* Wk      = (const float*)d_in[2];
  const float* Wv      = (const float*)d_in[3];
  const float* Wo      = (const float*)d_in[4];
  const float* q_scale = (const float*)d_in[5];
  const float* k_scale = (const float*)d_in[6];
  const float* cosb    = (const float*)d_in[7];
  const float* sinb    = (const float*)d_in[8];
  float* out = (float*)d_out;

  // Workspace overlays (peak 83.9 MB; round 1 proved >= 83.9 MB available):
  char* w = (char*)d_ws;
  unsigned short* x_bf = (unsigned short*)w;                  // [0, 16.78M)
  float* q             = (float*)(w + 16777216);              // [16.78M, 50.33M)
  float* kbuf          = (float*)(w + 50331648);              // [50.33M, 58.72M)
  float* vbuf          = (float*)(w + 58720256);              // [58.72M, 67.11M)
  unsigned short* wq_t = (unsigned short*)(w + 67108864);     // [67.11M, 75.50M)
  unsigned short* wk_t = (unsigned short*)(w + 75497472);     // [75.50M, 77.59M)
  unsigned short* wv_t = (unsigned short*)(w + 77594624);     // [77.59M, 79.69M)
  // overlays (regions dead by the time these go live):
  unsigned short* q_bf = (unsigned short*)(w + 67108864);     // over wq_t..wv_t (16.78M)
  unsigned short* k_bf = (unsigned short*)(w + 16777216);     // over q fp32 (4.19M)
  unsigned short* vt   = (unsigned short*)(w + 20971520);     // over q fp32 (4.19M)
  unsigned short* wo_t = (unsigned short*)(w + 25165824);     // over q fp32 (8.39M)
  unsigned short* attn_bf = (unsigned short*)w;               // over x_bf (16.78M)

  // Pre-pass: casts + weight transposes.
  cast_bf16<<<(4096 * 2048 / 4) / 256, 256, 0, stream>>>(x, x_bf);
  transpose_cast<<<dim3(2048 / 32, 2048 / 32), dim3(32, 8), 0, stream>>>(Wq, wq_t, 2048, 2048);
  transpose_cast<<<dim3(512 / 32, 2048 / 32), dim3(32, 8), 0, stream>>>(Wk, wk_t, 2048, 512);
  transpose_cast<<<dim3(512 / 32, 2048 / 32), dim3(32, 8), 0, stream>>>(Wv, wv_t, 2048, 512);

  // QKV projections (bf16 MFMA, fp32 out).
  gemm_bf16<<<dim3(2048 / 128, 4096 / 128), 256, 0, stream>>>(x_bf, wq_t, q, 4096, 2048, 2048);
  gemm_bf16<<<dim3(512 / 128, 4096 / 128), 256, 0, stream>>>(x_bf, wk_t, kbuf, 4096, 512, 2048);
  gemm_bf16<<<dim3(512 / 128, 4096 / 128), 256, 0, stream>>>(x_bf, wv_t, vbuf, 4096, 512, 2048);

  // RMSNorm + RoPE -> bf16 head-major; V -> bf16 transposed.
  rmsnorm_rope<<<dim3(4096, NHQ / 4), dim3(64, 4), 0, stream>>>(q, q_bf, NHQ, q_scale, cosb, sinb);
  rmsnorm_rope<<<dim3(4096, NHK / 4), dim3(64, 4), 0, stream>>>(kbuf, k_bf, NHK, k_scale, cosb, sinb);
  transpose_v<<<dim3(SEQ / 32, 128 / 32, 2 * NHK), dim3(32, 8), 0, stream>>>(vbuf, vt);

  // MFMA flash attention -> bf16 [b*L][H*128].
  attn_mfma<<<dim3(2 * NHQ, SEQ / 64), 256, 0, stream>>>(q_bf, k_bf, vt, attn_bf);

  // Output projection.
  transpose_cast<<<dim3(2048 / 32, 2048 / 32), dim3(32, 8), 0, stream>>>(Wo, wo_t, 2048, 2048);
  gemm_bf16<<<dim3(2048 / 128, 4096 / 128), 256, 0, stream>>>(attn_bf, wo_t, out, 4096, 2048, 2048);
}

// Round 4
// 381.416 us; speedup vs baseline: 7.4582x; 1.2527x over previous
//
#include <hip/hip_runtime.h>
#include <math.h>

// Problem constants (fixed by reference):
// B=2, L=2048, D=2048, H=16, G=4, HD=128, EPS=1e-6, scale = 1/HD^2 = 1/16384
#define SEQ 2048
#define DMODEL 2048
#define NHQ 16
#define NHK 4

typedef __attribute__((ext_vector_type(8))) short short8;
typedef __attribute__((ext_vector_type(4))) float floatx4;

__device__ __forceinline__ unsigned short f2bf(float f) {
  unsigned int u = __builtin_bit_cast(unsigned int, f);
  u += 0x7fffu + ((u >> 16) & 1u);   // round-to-nearest-even
  return (unsigned short)(u >> 16);
}

// ---------------------------------------------------------------------------
// cast fp32 -> bf16, 4 elements/thread.
// ---------------------------------------------------------------------------
__global__ __launch_bounds__(256) void cast_bf16(const float* __restrict__ in,
                                                 unsigned short* __restrict__ out) {
  const size_t i = ((size_t)blockIdx.x * 256 + threadIdx.x) * 4;
  const float4 v = *(const float4*)(in + i);
  ushort4 w;
  w.x = f2bf(v.x); w.y = f2bf(v.y); w.z = f2bf(v.z); w.w = f2bf(v.w);
  *(ushort4*)(out + i) = w;
}

// ---------------------------------------------------------------------------
// transpose + cast: in fp32 [R][C] -> out bf16 [C][R]. 32x32 LDS tile.
// ---------------------------------------------------------------------------
__global__ __launch_bounds__(256) void transpose_cast(const float* __restrict__ in,
                                                      unsigned short* __restrict__ out,
                                                      int R, int C) {
  __shared__ float tile[32][33];
  const int tx = threadIdx.x, ty = threadIdx.y;
  const int c0 = blockIdx.x * 32, r0 = blockIdx.y * 32;
#pragma unroll
  for (int j = 0; j < 4; ++j)
    tile[ty + j * 8][tx] = in[(size_t)(r0 + ty + j * 8) * C + c0 + tx];
  __syncthreads();
#pragma unroll
  for (int j = 0; j < 4; ++j)
    out[(size_t)(c0 + ty + j * 8) * R + r0 + tx] = f2bf(tile[tx][ty + j * 8]);
}

// ---------------------------------------------------------------------------
// V transpose from fused kv buffer: kv fp32 [b*L][1024] (V at cols 512+g*128+d)
// -> vt bf16 [(b*G+g)][128][L]. block (32,8), grid (L/32, 128/32, B*G).
// ---------------------------------------------------------------------------
__global__ __launch_bounds__(256) void transpose_v(const float* __restrict__ in,
                                                   unsigned short* __restrict__ out) {
  __shared__ float tile[32][33];
  const int tx = threadIdx.x, ty = threadIdx.y;
  const int l0 = blockIdx.x * 32, d0 = blockIdx.y * 32;
  const int bg = blockIdx.z;                 // b*4+g
  const int b = bg >> 2, g = bg & 3;
#pragma unroll
  for (int j = 0; j < 4; ++j)
    tile[ty + j * 8][tx] = in[(size_t)(b * SEQ + l0 + ty + j * 8) * 1024 + 512 + g * 128 + d0 + tx];
  __syncthreads();
#pragma unroll
  for (int j = 0; j < 4; ++j)
    out[((size_t)bg * 128 + d0 + ty + j * 8) * SEQ + l0 + tx] = f2bf(tile[tx][ty + j * 8]);
}

// ---------------------------------------------------------------------------
// bf16 MFMA GEMM (m97 structure): C[M][N] = A[M][K] @ B[K][N], fp32 out.
// ---------------------------------------------------------------------------
__global__ __launch_bounds__(256) void gemm_bf16(const unsigned short* __restrict__ A,
                                                 const unsigned short* __restrict__ Bt,
                                                 float* __restrict__ C,
                                                 int M, int N, int K) {
  __shared__ unsigned short As[128 * 32];
  __shared__ unsigned short Bs[128 * 32];
  const int tid = threadIdx.x;
  const int wave = tid >> 6;
  const int lane = tid & 63;
  const int bm = blockIdx.y * 128;
  const int bn = blockIdx.x * 128;
  const int wr = wave >> 1;
  const int wc = wave & 1;
  const int m15 = lane & 15;
  const int quad = lane >> 4;

  floatx4 acc[4][4];
#pragma unroll
  for (int i = 0; i < 4; ++i)
#pragma unroll
    for (int j = 0; j < 4; ++j) acc[i][j] = (floatx4){0.f, 0.f, 0.f, 0.f};

  const int srow = lane >> 2;
  const int scol = (lane & 3) * 8;

  for (int k0 = 0; k0 < K; k0 += 32) {
#pragma unroll
    for (int it = 0; it < 2; ++it) {
      const int rowa = wave * 32 + it * 16;
      const unsigned short* ga = A + (size_t)(bm + rowa + srow) * K + k0 + scol;
      const unsigned short* gb = Bt + (size_t)(bn + rowa + srow) * K + k0 + scol;
      __builtin_amdgcn_global_load_lds(
          (const __attribute__((address_space(1))) void*)ga,
          (__attribute__((address_space(3))) void*)&As[rowa * 32], 16, 0, 0);
      __builtin_amdgcn_global_load_lds(
          (const __attribute__((address_space(1))) void*)gb,
          (__attribute__((address_space(3))) void*)&Bs[rowa * 32], 16, 0, 0);
    }
    __syncthreads();

    short8 af[4], bfr[4];
    const unsigned short* pa = &As[(wr * 64 + m15) * 32 + quad * 8];
    const unsigned short* pb = &Bs[(wc * 64 + m15) * 32 + quad * 8];
#pragma unroll
    for (int i = 0; i < 4; ++i) af[i] = *(const short8*)(pa + i * 16 * 32);
#pragma unroll
    for (int j = 0; j < 4; ++j) bfr[j] = *(const short8*)(pb + j * 16 * 32);
#pragma unroll
    for (int i = 0; i < 4; ++i)
#pragma unroll
      for (int j = 0; j < 4; ++j)
        acc[i][j] = __builtin_amdgcn_mfma_f32_16x16x32_bf16(af[i], bfr[j], acc[i][j], 0, 0, 0);
    __syncthreads();
  }

#pragma unroll
  for (int i = 0; i < 4; ++i)
#pragma unroll
    for (int j = 0; j < 4; ++j) {
      const int col = bn + wc * 64 + j * 16 + m15;
#pragma unroll
      for (int reg = 0; reg < 4; ++reg) {
        const int row = bm + wr * 64 + i * 16 + quad * 4 + reg;
        C[(size_t)row * N + col] = acc[i][j][reg];
      }
    }
}

// ---------------------------------------------------------------------------
// Fused RMSNorm + RoPE: fp32 in (row stride rowHeads*128, head offset head*128)
// -> bf16 out [(b*NH+h)][l][128].
// ---------------------------------------------------------------------------
__global__ __launch_bounds__(256) void rmsnorm_rope(const float* __restrict__ in,
                                                    unsigned short* __restrict__ out,
                                                    int rowHeads, int NH,
                                                    const float* __restrict__ scale,
                                                    const float* __restrict__ cosb,
                                                    const float* __restrict__ sinb) {
  const int t = threadIdx.x;                       // 0..63
  const int head = blockIdx.y * 4 + threadIdx.y;
  const int row = blockIdx.x;                      // 0..B*L-1
  const int b = row >> 11;
  const int l = row & (SEQ - 1);
  const float* base = in + ((size_t)row * rowHeads + head) * 128;
  float v0 = base[t];
  float v1 = base[t + 64];
  float ss = v0 * v0 + v1 * v1;
#pragma unroll
  for (int m = 1; m < 64; m <<= 1) ss += __shfl_xor(ss, m);
  const float r = rsqrtf(ss * (1.0f / 128.0f) + 1e-6f);
  const float a0 = v0 * r * scale[t];
  const float a1 = v1 * r * scale[t + 64];
  const float c0 = cosb[(size_t)l * 128 + t];
  const float s0 = sinb[(size_t)l * 128 + t];
  const float c1 = cosb[(size_t)l * 128 + t + 64];
  const float s1 = sinb[(size_t)l * 128 + t + 64];
  unsigned short* dst = out + ((size_t)(b * NH + head) * SEQ + l) * 128;
  dst[t]      = f2bf(a0 * c0 - a1 * s0);
  dst[t + 64] = f2bf(a1 * c1 + a0 * s1);
}

// ---------------------------------------------------------------------------
// MFMA flash attention (causal GQA), no-max softmax.
// |s| = |q.k|/16384 <= 128/16384 = 0.0078 by Cauchy-Schwarz (rms-normed q,k,
// norm-preserving RoPE, unit scales) -> exp(s) can't overflow; running max,
// alpha rescale, and per-tile shuffle reductions all removed.
// Grid (B*H, L/64) with reversed y (longest rows first), 256 threads = 4 waves.
// Q frags live in registers (loaded direct from global, wave-private rows).
// LDS: Ks 16K + Vs 16K + Ps 9K = 42 KB -> 3 blocks/CU.
// ---------------------------------------------------------------------------
__global__ __launch_bounds__(256, 3) void attn_mfma(const unsigned short* __restrict__ qb,
                                                    const unsigned short* __restrict__ kb,
                                                    const unsigned short* __restrict__ vtb,
                                                    unsigned short* __restrict__ o) {
  __shared__ unsigned short Ks[64 * 128];
  __shared__ unsigned short Vs[128 * 64];
  __shared__ unsigned short Ps[64 * 72];

  const int tid = threadIdx.x;
  const int wave = tid >> 6;
  const int lane = tid & 63;
  const int m15 = lane & 15;
  const int quad = lane >> 4;
  const int bh = blockIdx.x;           // 0..31
  const int b = bh >> 4;
  const int h = bh & 15;
  const int g = h >> 2;
  const int q0 = ((int)gridDim.y - 1 - (int)blockIdx.y) * 64;  // longest first

  const unsigned short* qhead = qb + (size_t)bh * SEQ * 128;
  const unsigned short* khead = kb + (size_t)(b * NHK + g) * SEQ * 128;
  const unsigned short* vthead = vtb + (size_t)(b * NHK + g) * 128 * SEQ;

  // ---- Q fragments straight from global into registers (row = wave*16+m15).
  short8 qf[4];
  {
    const unsigned short* qp = qhead + (size_t)(q0 + wave * 16 + m15) * 128 + quad * 8;
#pragma unroll
    for (int ks = 0; ks < 4; ++ks) qf[ks] = *(const short8*)(qp + ks * 32);
  }

  floatx4 acc_o[8];
#pragma unroll
  for (int n = 0; n < 8; ++n) acc_o[n] = (floatx4){0.f, 0.f, 0.f, 0.f};
  float l_lane[4] = {0.f, 0.f, 0.f, 0.f};
  const float inv_scale = 1.0f / 16384.0f;

  for (int j0 = 0; j0 <= q0; j0 += 64) {
    // ---- stage K tile (64 x 128), chunk-XOR swizzle
#pragma unroll
    for (int t = 0; t < 4; ++t) {
      const int r = wave * 16 + t * 4 + (lane >> 4);
      const int cg = (lane & 15) ^ (r & 15);
      const unsigned short* src = khead + (size_t)(j0 + r) * 128 + cg * 8;
      __builtin_amdgcn_global_load_lds(
          (const __attribute__((address_space(1))) void*)src,
          (__attribute__((address_space(3))) void*)&Ks[(wave * 16 + t * 4) * 128], 16, 0, 0);
    }
    // ---- stage Vt tile (128 dims x 64 keys)
#pragma unroll
    for (int t = 0; t < 4; ++t) {
      const int d = wave * 32 + t * 8 + (lane >> 3);
      const int cg = (lane & 7) ^ (d & 7);
      const unsigned short* src = vthead + (size_t)d * SEQ + j0 + cg * 8;
      __builtin_amdgcn_global_load_lds(
          (const __attribute__((address_space(1))) void*)src,
          (__attribute__((address_space(3))) void*)&Vs[(wave * 32 + t * 8) * 64], 16, 0, 0);
    }
    __syncthreads();

    // ---- S = Q K^T
    floatx4 acc_s[4];
#pragma unroll
    for (int n = 0; n < 4; ++n) acc_s[n] = (floatx4){0.f, 0.f, 0.f, 0.f};
#pragma unroll
    for (int ks = 0; ks < 4; ++ks) {
#pragma unroll
      for (int n = 0; n < 4; ++n) {
        const short8 bfrag = *(const short8*)&Ks[(n * 16 + m15) * 128 + (((ks * 4 + quad) ^ m15) * 8)];
        acc_s[n] = __builtin_amdgcn_mfma_f32_16x16x32_bf16(qf[ks], bfrag, acc_s[n], 0, 0, 0);
      }
    }

    // ---- p = exp(s/16384); mask only on the diagonal tile.
    if (j0 == q0) {
      const int row_g = wave * 16 + quad * 4;        // + rg (relative to q0)
#pragma unroll
      for (int n = 0; n < 4; ++n) {
        const int col = n * 16 + m15;
#pragma unroll
        for (int rg = 0; rg < 4; ++rg) {
          float p = (col > row_g + rg) ? 0.0f : __expf(acc_s[n][rg] * inv_scale);
          l_lane[rg] += p;
          Ps[(wave * 16 + quad * 4 + rg) * 72 + n * 16 + m15] = f2bf(p);
        }
      }
    } else {
#pragma unroll
      for (int n = 0; n < 4; ++n) {
#pragma unroll
        for (int rg = 0; rg < 4; ++rg) {
          const float p = __expf(acc_s[n][rg] * inv_scale);
          l_lane[rg] += p;
          Ps[(wave * 16 + quad * 4 + rg) * 72 + n * 16 + m15] = f2bf(p);
        }
      }
    }

    // ---- O += P V  (Ps rows are wave-private; compiler orders LDS w->r)
#pragma unroll
    for (int kk = 0; kk < 2; ++kk) {
      const short8 a = *(const short8*)&Ps[(wave * 16 + m15) * 72 + kk * 32 + quad * 8];
#pragma unroll
      for (int n = 0; n < 8; ++n) {
        const short8 bfrag = *(const short8*)&Vs[(n * 16 + m15) * 64 + (((kk * 4 + quad) ^ (m15 & 7)) * 8)];
        acc_o[n] = __builtin_amdgcn_mfma_f32_16x16x32_bf16(a, bfrag, acc_o[n], 0, 0, 0);
      }
    }
    __syncthreads();
  }

  // ---- final l reduction across the 16 m15 lanes, then epilogue.
#pragma unroll
  for (int rg = 0; rg < 4; ++rg) {
    float l = l_lane[rg];
    l += __shfl_xor(l, 1);
    l += __shfl_xor(l, 2);
    l += __shfl_xor(l, 4);
    l += __shfl_xor(l, 8);
    const float invl = 1.0f / l;
    const size_t row = (size_t)(b * SEQ + q0 + wave * 16 + quad * 4 + rg);
#pragma unroll
    for (int n = 0; n < 8; ++n)
      o[row * DMODEL + h * 128 + n * 16 + m15] = f2bf(acc_o[n][rg] * invl);
  }
}

// ---------------------------------------------------------------------------
extern "C" void kernel_launch(void* const* d_in, const int* in_sizes, int n_in,
                              void* d_out, int out_size, void* d_ws, size_t ws_size,
                              hipStream_t stream) {
  const float* x       = (const float*)d_in[0];
  const float* Wq      = (const float*)d_in[1];
  const float* Wk      = (const float*)d_in[2];
  const float* Wv      = (const float*)d_in[3];
  const float* Wo      = (const float*)d_in[4];
  const float* q_scale = (const float*)d_in[5];
  const float* k_scale = (const float*)d_in[6];
  const float* cosb    = (const float*)d_in[7];
  const float* sinb    = (const float*)d_in[8];
  float* out = (float*)d_out;

  // Workspace overlays (peak 83.9 MB, proven available in R1-R3):
  char* w = (char*)d_ws;
  unsigned short* x_bf  = (unsigned short*)w;                 // [0, 16.78M)
  float* q              = (float*)(w + 16777216);             // [16.78M, 50.33M)
  float* kv             = (float*)(w + 50331648);             // [50.33M, 67.11M)  [4096][1024]
  unsigned short* wq_t  = (unsigned short*)(w + 67108864);    // [67.11M, 75.50M)
  unsigned short* wkv_t = (unsigned short*)(w + 75497472);    // [75.50M, 79.69M)  [1024][2048]
  // overlays (regions dead when these go live):
  unsigned short* q_bf = (unsigned short*)(w + 67108864);     // over wq_t+wkv_t (16.78M)
  unsigned short* k_bf = (unsigned short*)(w + 16777216);     // over q fp32 (4.19M)
  unsigned short* vt   = (unsigned short*)(w + 20971520);     // over q fp32 (4.19M)
  unsigned short* wo_t = (unsigned short*)(w + 25165824);     // over q fp32 (8.39M)
  unsigned short* attn_bf = (unsigned short*)w;               // over x_bf (16.78M)

  // Pre-pass: casts + weight transposes (Wk,Wv concatenated -> one GEMM).
  cast_bf16<<<(4096 * 2048 / 4) / 256, 256, 0, stream>>>(x, x_bf);
  transpose_cast<<<dim3(2048 / 32, 2048 / 32), dim3(32, 8), 0, stream>>>(Wq, wq_t, 2048, 2048);
  transpose_cast<<<dim3(512 / 32, 2048 / 32), dim3(32, 8), 0, stream>>>(Wk, wkv_t, 2048, 512);
  transpose_cast<<<dim3(512 / 32, 2048 / 32), dim3(32, 8), 0, stream>>>(Wv, wkv_t + (size_t)512 * 2048, 2048, 512);

  // Projections: Q (N=2048) and fused K|V (N=1024).
  gemm_bf16<<<dim3(2048 / 128, 4096 / 128), 256, 0, stream>>>(x_bf, wq_t, q, 4096, 2048, 2048);
  gemm_bf16<<<dim3(1024 / 128, 4096 / 128), 256, 0, stream>>>(x_bf, wkv_t, kv, 4096, 1024, 2048);

  // RMSNorm + RoPE -> bf16 head-major; V -> bf16 transposed.
  rmsnorm_rope<<<dim3(4096, NHQ / 4), dim3(64, 4), 0, stream>>>(q, q_bf, 16, NHQ, q_scale, cosb, sinb);
  rmsnorm_rope<<<dim3(4096, NHK / 4), dim3(64, 4), 0, stream>>>(kv, k_bf, 8, NHK, k_scale, cosb, sinb);
  transpose_v<<<dim3(SEQ / 32, 128 / 32, 2 * NHK), dim3(32, 8), 0, stream>>>(kv, vt);

  // Wo transpose (over dead q fp32), then attention, then output projection.
  transpose_cast<<<dim3(2048 / 32, 2048 / 32), dim3(32, 8), 0, stream>>>(Wo, wo_t, 2048, 2048);
  attn_mfma<<<dim3(2 * NHQ, SEQ / 64), 256, 0, stream>>>(q_bf, k_bf, vt, attn_bf);
  gemm_bf16<<<dim3(2048 / 128, 4096 / 128), 256, 0, stream>>>(attn_bf, wo_t, out, 4096, 2048, 2048);
}